// Round 2
// baseline (193.661 us; speedup 1.0000x reference)
//
#include <hip/hip_runtime.h>

// CompactPiecewiseLinearEmbeddings: out[n,f,:] = C[f][k] + t*(C[f][k+1]-C[f][k])
// where k = #{j in [1,47] : edges[f][j] <= x[n,f]}, t = (x - edges[f][k]) / width[f][k],
// C[f][j] = bias[f] + sum_{b<j} W[f][b][:]   (sorted boundaries => h = [1..1, t, 0..0])
//
// R2: store-coalescing rewrite. Each (n,f) is split across a lane PAIR
// (half = d0-3 / d4-7) so one global_store_dwordx4 from a wave covers
// 2 rows x 512 B fully-contiguous output (16 complete cache lines) --
// no partial-line RMW at L2/HBM. NSPLIT 128->64 amortizes the prologue
// (32 main passes/block instead of 4).

#define NN 16384
#define FF 256
#define BB 48
#define DD 8

#define FT 16              // features per block
#define NSPLIT 64          // n-splits
#define NPB (NN / NSPLIT)  // 256 rows per block

#define ESTR 17            // [j][ESTR] transposed edge table stride (coprime to 32 banks)
#define CSTR (49 * DD + 4) // 396 floats per feature (pad +4 breaks 8f mod-32 bank pattern)

__global__ __launch_bounds__(256, 4)
void cple_kernel(const float* __restrict__ X,
                 const float* __restrict__ Edg,
                 const float* __restrict__ Wid,
                 const float* __restrict__ W,
                 const float* __restrict__ Bias,
                 float* __restrict__ Out)
{
    __shared__ float sE[49 * ESTR];   // edges transposed, j=0..48 (48 = +inf sentinel)
    __shared__ float sR[48 * ESTR];   // 1/width transposed
    __shared__ float sC[FT * CSTR];   // cumulative W + bias, [f][j=0..48][d]

    const int tid = threadIdx.x;
    const int f0  = blockIdx.x * FT;
    const int ns  = blockIdx.y;

    // --- stage W tile into sC at [f][b+1][d] (contiguous 6144-float chunk, float4) ---
    {
        const float4* Wt4 = (const float4*)(W + (size_t)f0 * BB * DD);
        for (int idx4 = tid; idx4 < FT * BB * DD / 4; idx4 += 256) {
            float4 v = Wt4[idx4];
            int idx = idx4 * 4;
            int f   = idx / (BB * DD);
            int rem = idx - f * (BB * DD);
            int b   = rem >> 3;
            int d   = rem & 7;
            float* dst = &sC[f * CSTR + (b + 1) * DD + d];
            dst[0] = v.x; dst[1] = v.y; dst[2] = v.z; dst[3] = v.w;
        }
    }
    // --- stage edges & reciprocal widths (transposed) ---
    for (int idx = tid; idx < FT * BB; idx += 256) {
        int f = idx / BB;
        int j = idx - f * BB;
        sE[j * ESTR + f] = Edg[(size_t)(f0 + f) * BB + j];
        sR[j * ESTR + f] = 1.0f / Wid[(size_t)(f0 + f) * BB + j];
    }
    if (tid < FT) sE[48 * ESTR + tid] = __builtin_inff();  // sentinel for probe j=48
    __syncthreads();

    // --- in-place inclusive scan: C[f][j][d] = bias + sum_{b<j} W[f][b][d] ---
    if (tid < FT * DD) {
        int f = tid >> 3;
        int d = tid & 7;
        float acc = Bias[(size_t)(f0 + f) * DD + d];
        float* c = &sC[f * CSTR + d];
        c[0] = acc;
        #pragma unroll
        for (int b = 1; b <= BB; ++b) {
            acc += c[b * DD];   // holds W[f][b-1][d]
            c[b * DD] = acc;
        }
    }
    __syncthreads();

    // --- main loop ---
    // slot 0..31 covers one output row-patch of 512 B: f = slot>>1, half = slot&1.
    // 256 threads = 8 rows per pass; 32 passes.
    const int slot = tid & 31;
    const int f_l  = slot >> 1;
    const int half = slot & 1;
    const int r    = tid >> 5;          // 0..7

    const float* cF = &sC[f_l * CSTR + half * 4];
    const int fcol  = f0 + f_l;
    const float* xp = X + fcol;                          // + n*FF
    float* op = Out + (size_t)f0 * DD + slot * 4;        // + n*FF*DD

    const int n0 = ns * NPB + r;
    #pragma unroll 4
    for (int i = 0; i < NPB / 8; ++i) {
        int n = n0 + i * 8;
        float x = xp[(size_t)n * FF];

        // branchless binary search: k = count of edges[1..47] <= x  (paired lanes
        // share x -> identical LDS addresses -> broadcast, no conflict)
        int k = 0;
        #pragma unroll
        for (int w = 32; w >= 1; w >>= 1)
            k += (x >= sE[(k + w) * ESTR + f_l]) ? w : 0;
        float t = (x - sE[k * ESTR + f_l]) * sR[k * ESTR + f_l];

        float4 lo = *(const float4*)(cF + k * DD);
        float4 hi = *(const float4*)(cF + k * DD + DD);
        float4 o;
        o.x = fmaf(t, hi.x - lo.x, lo.x);
        o.y = fmaf(t, hi.y - lo.y, lo.y);
        o.z = fmaf(t, hi.z - lo.z, lo.z);
        o.w = fmaf(t, hi.w - lo.w, lo.w);

        *(float4*)(op + (size_t)n * (FF * DD)) = o;   // wave: 2 rows x 512 B contiguous
    }
}

extern "C" void kernel_launch(void* const* d_in, const int* in_sizes, int n_in,
                              void* d_out, int out_size, void* d_ws, size_t ws_size,
                              hipStream_t stream) {
    const float* x     = (const float*)d_in[0];
    const float* edges = (const float*)d_in[1];
    const float* width = (const float*)d_in[2];
    const float* W     = (const float*)d_in[3];
    const float* b     = (const float*)d_in[4];
    float* out = (float*)d_out;

    dim3 grid(FF / FT, NSPLIT);
    cple_kernel<<<grid, 256, 0, stream>>>(x, edges, width, W, b, out);
}